// Round 9
// baseline (349.332 us; speedup 1.0000x reference)
//
#include <hip/hip_runtime.h>

#define N_NODES_C 50000
#define N_EDGES_C 800000
#define IN_FEATS_C 128
#define HEADS_C 8
#define HD_C 256            // HEADS * OUT_FEATS
#define NEG_SLOPE_C 0.2f
#define SCAN_NBLK 49        // ceil(50000/1024)
#define LDT 136             // LDS row stride in shorts (272 B = 17*16, 16B-aligned)

#define GEMM_BLOCKS 782     // ceil(50000/128) * 2 channel tiles
#define DEG_BLOCKS 242
#define K1_GRID (GEMM_BLOCKS + DEG_BLOCKS)   // 1024

typedef __attribute__((ext_vector_type(8))) short bf16x8;
typedef __attribute__((ext_vector_type(4))) float floatx4;

__device__ inline unsigned short f2bf(float f) {
  unsigned int u = __float_as_uint(f);
  unsigned int r = (u + 0x7FFFu + ((u >> 16) & 1u)) >> 16;   // RNE
  return (unsigned short)r;
}
__device__ inline float bf2f(unsigned short s) {
  unsigned int u = ((unsigned int)s) << 16;
  return __uint_as_float(u);
}

// 49-entry exclusive scan of bsum into sboff[64] (first wave only, then barrier)
__device__ inline void boff_scan(const int* __restrict__ bsum, int* sboff) {
  int t = threadIdx.x;
  if (t < 64) {
    int own = (t < SCAN_NBLK) ? bsum[t] : 0;
    int v = own;
#pragma unroll
    for (int off = 1; off < 64; off <<= 1) {
      int u = __shfl_up(v, off);
      if (t >= off) v += u;
    }
    sboff[t] = v - own;   // exclusive
  }
  __syncthreads();
}

// ============ prep: fused {W fp32->bf16 conversion, deg zeroing} ============
__global__ __launch_bounds__(256) void prep_kernel(
    const float* __restrict__ W, unsigned short* __restrict__ Wbf,
    int* __restrict__ deg) {
  int b = blockIdx.x, t = threadIdx.x;
  if (b < 32) {
    int i = (b * 256 + t) * 4;
    float4 v = *(const float4*)&W[i];
    ushort4 o;
    o.x = f2bf(v.x); o.y = f2bf(v.y); o.z = f2bf(v.z); o.w = f2bf(v.w);
    *(ushort4*)&Wbf[i] = o;
  } else {
    int i = ((b - 32) * 256 + t) * 4;
    if (i < N_NODES_C) {
      if (i + 4 <= N_NODES_C)
        *(int4*)&deg[i] = make_int4(0, 0, 0, 0);
      else
        for (int k = i; k < N_NODES_C; ++k) deg[k] = 0;
    }
  }
}

// ============ K1: deg+rank histogram (0..241) || MFMA gemm + fused el/er ============
// Identical to the round-6 best except the epilogue writes HEAD-MAJOR layouts:
// feat_hd_T[h][node][32], el_T[h][node], er_T[h][node] — enables XCD-sharded
// L2-resident gathers in agg.
__global__ __launch_bounds__(256) void front_kernel(
    const float* __restrict__ feat, const unsigned short* __restrict__ Wbf,
    const float* __restrict__ attn_l, const float* __restrict__ attn_r,
    const int* __restrict__ dst,
    unsigned short* __restrict__ feat_hd_T,
    float* __restrict__ el_T, float* __restrict__ er_T,
    int* __restrict__ deg, int* __restrict__ rank) {
  __shared__ __align__(16) unsigned short sA[128 * LDT];   // 34816 B; reused as sOut
  __shared__ float sAttnL[128];
  __shared__ float sAttnR[128];
  const int bid = blockIdx.x;
  const int t = threadIdx.x;

  if (bid < DEG_BLOCKS) {
    // ---- degree histogram + rank capture, 8 atomics in flight ----
    for (int e0 = (bid * 256 + t) * 8; e0 < N_EDGES_C; e0 += DEG_BLOCKS * 2048) {
      int4 da = *(const int4*)&dst[e0];
      int4 db = *(const int4*)&dst[e0 + 4];
      int r0 = atomicAdd(&deg[da.x], 1);
      int r1 = atomicAdd(&deg[da.y], 1);
      int r2 = atomicAdd(&deg[da.z], 1);
      int r3 = atomicAdd(&deg[da.w], 1);
      int r4 = atomicAdd(&deg[db.x], 1);
      int r5 = atomicAdd(&deg[db.y], 1);
      int r6 = atomicAdd(&deg[db.z], 1);
      int r7 = atomicAdd(&deg[db.w], 1);
      *(int4*)&rank[e0]     = make_int4(r0, r1, r2, r3);
      *(int4*)&rank[e0 + 4] = make_int4(r4, r5, r6, r7);
    }
    return;
  }

  const int gb = bid - DEG_BLOCKS;     // 0..781
  int mt, nt;
  if (gb < 768) {
    mt = ((gb >> 4) << 3) + (gb & 7);  // twins 8 apart: same XCD, feat L2-hits
    nt = (gb >> 3) & 1;
  } else {
    int l = gb - 768;
    nt = (l >= 7) ? 1 : 0;
    mt = 384 + (nt ? l - 7 : l);
  }
  const int m0 = mt * 128;
  const int n0 = nt * 128;

  if (t < 128) {
    sAttnL[t] = attn_l[n0 + t];
    sAttnR[t] = attn_r[n0 + t];
  }
  // stage A: 128 rows x 32 float4 of feat -> bf16
#pragma unroll
  for (int i = 0; i < 16; ++i) {
    int idx = t + i * 256;
    int row = idx >> 5;
    int c4 = idx & 31;
    int gn = m0 + row;
    float4 v = (gn < N_NODES_C)
                   ? *(const float4*)&feat[(size_t)gn * IN_FEATS_C + c4 * 4]
                   : make_float4(0.f, 0.f, 0.f, 0.f);
    ushort4 b;
    b.x = f2bf(v.x); b.y = f2bf(v.y); b.z = f2bf(v.z); b.w = f2bf(v.w);
    *(ushort4*)&sA[row * LDT + c4 * 4] = b;
  }
  __syncthreads();

  const int wid = t >> 6;
  const int lane = t & 63;
  const int quad = lane >> 4;
  const int l16 = lane & 15;
  const int wm = (wid & 1) * 64;
  const int wn = (wid >> 1) * 64;

  floatx4 acc[4][4];
#pragma unroll
  for (int i = 0; i < 4; ++i)
#pragma unroll
    for (int j = 0; j < 4; ++j) acc[i][j] = (floatx4){0.f, 0.f, 0.f, 0.f};

#pragma unroll
  for (int ks = 0; ks < 4; ++ks) {
    int k0 = ks * 32 + quad * 8;
    bf16x8 bfv[4];
#pragma unroll
    for (int n2 = 0; n2 < 4; ++n2)
      bfv[n2] = *(const bf16x8*)&Wbf[(size_t)(n0 + wn + n2 * 16 + l16) *
                                         IN_FEATS_C + k0];
    bf16x8 af[4];
#pragma unroll
    for (int m2 = 0; m2 < 4; ++m2)
      af[m2] = *(const bf16x8*)&sA[(wm + m2 * 16 + l16) * LDT + k0];
#pragma unroll
    for (int m2 = 0; m2 < 4; ++m2)
#pragma unroll
      for (int n2 = 0; n2 < 4; ++n2)
        acc[m2][n2] = __builtin_amdgcn_mfma_f32_16x16x32_bf16(
            af[m2], bfv[n2], acc[m2][n2], 0, 0, 0);
  }
  __syncthreads();

  // epilogue: D layout col=l16, row=quad*4+reg -> repack via LDS
#pragma unroll
  for (int m2 = 0; m2 < 4; ++m2)
#pragma unroll
    for (int n2 = 0; n2 < 4; ++n2)
#pragma unroll
      for (int r = 0; r < 4; ++r) {
        int row = wm + m2 * 16 + quad * 4 + r;
        int col = wn + n2 * 16 + l16;
        sA[row * LDT + col] = f2bf(acc[m2][n2][r]);
      }
  __syncthreads();

  // head-major store of the bf16 tile: feat_hd_T[h][node][32]
  // 16B chunk (8 ch) never crosses a 32-ch head boundary.
#pragma unroll
  for (int i = 0; i < 8; ++i) {
    int idx = t + i * 256;
    int row = idx >> 4;
    int ch = idx & 15;
    int gn = m0 + row;
    if (gn < N_NODES_C) {
      int gc = n0 + ch * 8;
      int hh2 = gc >> 5;
      int co = gc & 31;
      *(uint4*)&feat_hd_T[((size_t)hh2 * N_NODES_C + gn) * 32 + co] =
          *(const uint4*)&sA[row * LDT + ch * 8];
    }
  }

  // fused el/er -> transposed tables el_T[h][node], er_T[h][node]
  {
    int row = t >> 1;
    int hh = t & 1;
    int gn = m0 + row;
    if (gn < N_NODES_C) {
      const unsigned short* pr = &sA[row * LDT + hh * 64];
      const float* al = &sAttnL[hh * 64];
      const float* ar = &sAttnR[hh * 64];
      float el0 = 0.f, el1 = 0.f, er0 = 0.f, er1 = 0.f;
#pragma unroll
      for (int d8 = 0; d8 < 4; ++d8) {
        bf16x8 v0 = *(const bf16x8*)&pr[d8 * 8];
        bf16x8 v1 = *(const bf16x8*)&pr[32 + d8 * 8];
#pragma unroll
        for (int j = 0; j < 8; ++j) {
          float f0 = bf2f((unsigned short)v0[j]);
          float f1 = bf2f((unsigned short)v1[j]);
          el0 = fmaf(f0, al[d8 * 8 + j], el0);
          er0 = fmaf(f0, ar[d8 * 8 + j], er0);
          el1 = fmaf(f1, al[32 + d8 * 8 + j], el1);
          er1 = fmaf(f1, ar[32 + d8 * 8 + j], er1);
        }
      }
      int gh = nt * 4 + hh * 2;
      el_T[(size_t)(gh + 0) * N_NODES_C + gn] = el0;
      el_T[(size_t)(gh + 1) * N_NODES_C + gn] = el1;
      er_T[(size_t)(gh + 0) * N_NODES_C + gn] = er0;
      er_T[(size_t)(gh + 1) * N_NODES_C + gn] = er1;
    }
  }
}

// ============ scan1: emits packed {row_start_incl, deg} int2 ============
__global__ __launch_bounds__(256) void scan1_kernel(
    const int* __restrict__ deg, int2* __restrict__ rsd,
    int* __restrict__ bsum) {
  __shared__ int s[256];
  int b = blockIdx.x, t = threadIdx.x;
  int i0 = b * 1024 + t * 4;
  int d0 = 0, d1 = 0, d2 = 0, d3 = 0;
  if (i0 + 4 <= N_NODES_C) {
    int4 d = *(const int4*)&deg[i0];
    d0 = d.x; d1 = d.y; d2 = d.z; d3 = d.w;
  } else {
    if (i0 + 0 < N_NODES_C) d0 = deg[i0 + 0];
    if (i0 + 1 < N_NODES_C) d1 = deg[i0 + 1];
    if (i0 + 2 < N_NODES_C) d2 = deg[i0 + 2];
    if (i0 + 3 < N_NODES_C) d3 = deg[i0 + 3];
  }
  int l1 = d0, l2 = l1 + d1, l3 = l2 + d2, l4 = l3 + d3;
  s[t] = l4;
  __syncthreads();
#pragma unroll
  for (int off = 1; off < 256; off <<= 1) {
    int add = (t >= off) ? s[t - off] : 0;
    __syncthreads();
    s[t] += add;
    __syncthreads();
  }
  int excl = s[t] - l4;
  if (i0 + 0 < N_NODES_C) rsd[i0 + 0] = make_int2(excl + l1, d0);
  if (i0 + 1 < N_NODES_C) rsd[i0 + 1] = make_int2(excl + l2, d1);
  if (i0 + 2 < N_NODES_C) rsd[i0 + 2] = make_int2(excl + l3, d2);
  if (i0 + 3 < N_NODES_C) rsd[i0 + 3] = make_int2(excl + l4, d3);
  if (t == 255) bsum[b] = s[255];
}

// ============ scatter: atomic-free, 4 edges/thread ============
__global__ __launch_bounds__(256) void scatter_kernel(
    const int* __restrict__ src, const int* __restrict__ dst,
    const int2* __restrict__ rsd, const int* __restrict__ bsum,
    const int* __restrict__ rank, int* __restrict__ csr_src) {
  __shared__ int sboff[64];
  boff_scan(bsum, sboff);
  int base = (blockIdx.x * 256 + threadIdx.x) * 4;
  if (base >= N_EDGES_C) return;           // N_EDGES_C % 4 == 0 -> full int4
  int4 d4 = *(const int4*)&dst[base];
  int4 r4 = *(const int4*)&rank[base];
  int4 s4 = *(const int4*)&src[base];
  int2 v0 = rsd[d4.x];
  int2 v1 = rsd[d4.y];
  int2 v2 = rsd[d4.z];
  int2 v3 = rsd[d4.w];
  csr_src[v0.x - v0.y + sboff[d4.x >> 10] + r4.x] = s4.x;
  csr_src[v1.x - v1.y + sboff[d4.y >> 10] + r4.y] = s4.y;
  csr_src[v2.x - v2.y + sboff[d4.z >> 10] + r4.z] = s4.z;
  csr_src[v3.x - v3.y + sboff[d4.w >> 10] + r4.w] = s4.w;
}

// ============ agg: XCD-sharded per-head aggregation ============
// Block (bid&7)=head h -> XCD h under round-robin dispatch. Per-XCD working
// set = its feat_hd_T slice (3.2 MB) + el_T column (200 KB) -> L2-RESIDENT.
// Wave = one (node, head); lane = (j8 edge-slot, c8 channel-quad).
// One ushort4 gather per lane per 8-edge iter (8 distinct 64B lines/wave),
// 8x the waves of the old structure -> 8x outstanding requests. csr_src is
// streamed 8x total, nontemporal to avoid evicting the resident slice.
__global__ __launch_bounds__(256) void agg_csr_kernel(
    const unsigned short* __restrict__ feat_hd_T, const float* __restrict__ el_T,
    const float* __restrict__ er_T, const int2* __restrict__ rsd,
    const int* __restrict__ bsum, const int* __restrict__ csr_src,
    float* __restrict__ out) {
  __shared__ int sboff[64];
  boff_scan(bsum, sboff);
  const int bid = blockIdx.x;
  const int h = bid & 7;                       // == XCD id (round-robin)
  const int node = (bid >> 3) * 4 + (threadIdx.x >> 6);
  if (node >= N_NODES_C) return;
  const int lane = threadIdx.x & 63;
  const int j8 = lane >> 3;                    // edge slot 0..7
  const int c8 = lane & 7;                     // channel quad (4 ch each)
  const unsigned short* fh = feat_hd_T + (size_t)h * N_NODES_C * 32;
  const float* elh = el_T + (size_t)h * N_NODES_C;
  float er_d = er_T[(size_t)h * N_NODES_C + node];
  int2 v = rsd[node];
  int dg = v.y;
  int rs = v.x - dg + sboff[node >> 10];
  float4 acc = make_float4(0.f, 0.f, 0.f, 0.f);
  float zsum = 0.f;

  int nb = (dg + 7) >> 3;
  if (nb > 0) {
    const int last = dg - 1;
    int myidx = __builtin_nontemporal_load(&csr_src[rs + min(j8, last)]);
    for (int b = 0; b < nb; ++b) {
      int e0 = b * 8;
      // 64B row-slice gather: 8 distinct lines per wave, one instr
      ushort4 f = *(const ushort4*)&fh[(size_t)myidx * 32 + c8 * 4];
      float x = elh[myidx] + er_d;
      x = x > 0.f ? x : NEG_SLOPE_C * x;
      float w = (e0 + j8 < dg) ? __expf(x) : 0.f;
      int nidx = __builtin_nontemporal_load(
          &csr_src[rs + min(e0 + 8 + j8, last)]);
      zsum += w;
      acc.x = fmaf(w, bf2f(f.x), acc.x);
      acc.y = fmaf(w, bf2f(f.y), acc.y);
      acc.z = fmaf(w, bf2f(f.z), acc.z);
      acc.w = fmaf(w, bf2f(f.w), acc.w);
      myidx = nidx;
    }
    // reduce across the 8 edge-slot groups (lanes sharing c8)
#pragma unroll
    for (int off = 8; off < 64; off <<= 1) {
      zsum += __shfl_xor(zsum, off);
      acc.x += __shfl_xor(acc.x, off);
      acc.y += __shfl_xor(acc.y, off);
      acc.z += __shfl_xor(acc.z, off);
      acc.w += __shfl_xor(acc.w, off);
    }
  }

  float inv = (dg > 0) ? 1.f / zsum : 0.f;
  if (j8 == 0) {   // lanes 0..7 store 8 x float4 = 128 B contiguous
    *(float4*)&out[(size_t)node * HD_C + h * 32 + c8 * 4] =
        make_float4(acc.x * inv, acc.y * inv, acc.z * inv, acc.w * inv);
  }
}

extern "C" void kernel_launch(void* const* d_in, const int* in_sizes, int n_in,
                              void* d_out, int out_size, void* d_ws, size_t ws_size,
                              hipStream_t stream) {
  const float* feat   = (const float*)d_in[0];
  const float* W      = (const float*)d_in[1];
  const float* attn_l = (const float*)d_in[2];
  const float* attn_r = (const float*)d_in[3];
  const int* src      = (const int*)d_in[4];
  const int* dst      = (const int*)d_in[5];
  float* out = (float*)d_out;

  char* ws = (char*)d_ws;
  unsigned short* feat_hd_T = (unsigned short*)ws;   ws += (size_t)N_NODES_C * HD_C * 2;     // 25.6 MB, [8][N][32]
  float* el_T    = (float*)ws;                       ws += (size_t)N_NODES_C * HEADS_C * 4;  // 1.6 MB, [8][N]
  float* er_T    = (float*)ws;                       ws += (size_t)N_NODES_C * HEADS_C * 4;  // 1.6 MB, [8][N]
  int* deg       = (int*)ws;                         ws += (size_t)N_NODES_C * 4;
  int2* rsd      = (int2*)ws;                        ws += (size_t)N_NODES_C * 8;            // packed {row_start, deg}
  int* bsum      = (int*)ws;                         ws += 64 * 4;
  int* csr_src   = (int*)ws;                         ws += (size_t)N_EDGES_C * 4;            // 3.2 MB
  int* rank      = (int*)ws;                         ws += (size_t)N_EDGES_C * 4;            // 3.2 MB
  unsigned short* Wbf = (unsigned short*)ws;         ws += (size_t)HD_C * IN_FEATS_C * 2;    // 64 KB

  prep_kernel<<<81, 256, 0, stream>>>(W, Wbf, deg);

  front_kernel<<<K1_GRID, 256, 0, stream>>>(feat, Wbf, attn_l, attn_r, dst,
                                            feat_hd_T, el_T, er_T, deg, rank);

  scan1_kernel<<<SCAN_NBLK, 256, 0, stream>>>(deg, rsd, bsum);

  scatter_kernel<<<(N_EDGES_C / 4 + 255) / 256, 256, 0, stream>>>(
      src, dst, rsd, bsum, rank, csr_src);

  // 8 head-shards x 12500 node-groups; (bid & 7) pins a head to one XCD
  agg_csr_kernel<<<8 * ((N_NODES_C + 3) / 4), 256, 0, stream>>>(
      feat_hd_T, el_T, er_T, rsd, bsum, csr_src, out);
}

// Round 10
// 227.956 us; speedup vs baseline: 1.5325x; 1.5325x over previous
//
#include <hip/hip_runtime.h>

#define N_NODES_C 50000
#define N_EDGES_C 800000
#define IN_FEATS_C 128
#define HEADS_C 8
#define HD_C 256            // HEADS * OUT_FEATS
#define NEG_SLOPE_C 0.2f
#define SCAN_NBLK 49        // ceil(50000/1024)
#define LDT 136             // LDS row stride in shorts (272 B = 17*16, 16B-aligned)

#define GEMM_BLOCKS 782     // ceil(50000/128) * 2 channel tiles
#define DEG_BLOCKS 242
#define K1_GRID (GEMM_BLOCKS + DEG_BLOCKS)   // 1024

typedef __attribute__((ext_vector_type(8))) short bf16x8;
typedef __attribute__((ext_vector_type(4))) float floatx4;
typedef __attribute__((ext_vector_type(4))) int intx4;

__device__ inline unsigned short f2bf(float f) {
  unsigned int u = __float_as_uint(f);
  unsigned int r = (u + 0x7FFFu + ((u >> 16) & 1u)) >> 16;   // RNE
  return (unsigned short)r;
}
__device__ inline float bf2f(unsigned short s) {
  unsigned int u = ((unsigned int)s) << 16;
  return __uint_as_float(u);
}

// 49-entry exclusive scan of bsum into sboff[64] (first wave only, then barrier)
__device__ inline void boff_scan(const int* __restrict__ bsum, int* sboff) {
  int t = threadIdx.x;
  if (t < 64) {
    int own = (t < SCAN_NBLK) ? bsum[t] : 0;
    int v = own;
#pragma unroll
    for (int off = 1; off < 64; off <<= 1) {
      int u = __shfl_up(v, off);
      if (t >= off) v += u;
    }
    sboff[t] = v - own;   // exclusive
  }
  __syncthreads();
}

// ============ prep: fused {W fp32->bf16 conversion, deg zeroing} ============
__global__ __launch_bounds__(256) void prep_kernel(
    const float* __restrict__ W, unsigned short* __restrict__ Wbf,
    int* __restrict__ deg) {
  int b = blockIdx.x, t = threadIdx.x;
  if (b < 32) {
    int i = (b * 256 + t) * 4;
    float4 v = *(const float4*)&W[i];
    ushort4 o;
    o.x = f2bf(v.x); o.y = f2bf(v.y); o.z = f2bf(v.z); o.w = f2bf(v.w);
    *(ushort4*)&Wbf[i] = o;
  } else {
    int i = ((b - 32) * 256 + t) * 4;
    if (i < N_NODES_C) {
      if (i + 4 <= N_NODES_C)
        *(int4*)&deg[i] = make_int4(0, 0, 0, 0);
      else
        for (int k = i; k < N_NODES_C; ++k) deg[k] = 0;
    }
  }
}

// ============ K1: deg+rank histogram (0..241) || MFMA gemm + fused el/er ============
// Round-6 best: batched atomics-with-return histogram; GEMM with prepacked
// Wbf and twin channel-tile blocks 8 bids apart (same XCD -> feat L2-hits).
__global__ __launch_bounds__(256) void front_kernel(
    const float* __restrict__ feat, const unsigned short* __restrict__ Wbf,
    const float* __restrict__ attn_l, const float* __restrict__ attn_r,
    const int* __restrict__ dst,
    unsigned short* __restrict__ feat_hd_bf,
    float* __restrict__ el, float* __restrict__ er,
    int* __restrict__ deg, int* __restrict__ rank) {
  __shared__ __align__(16) unsigned short sA[128 * LDT];   // 34816 B; reused as sOut
  __shared__ float sAttnL[128];
  __shared__ float sAttnR[128];
  const int bid = blockIdx.x;
  const int t = threadIdx.x;

  if (bid < DEG_BLOCKS) {
    // ---- degree histogram + rank capture, 8 atomics in flight ----
    for (int e0 = (bid * 256 + t) * 8; e0 < N_EDGES_C; e0 += DEG_BLOCKS * 2048) {
      int4 da = *(const int4*)&dst[e0];
      int4 db = *(const int4*)&dst[e0 + 4];
      int r0 = atomicAdd(&deg[da.x], 1);
      int r1 = atomicAdd(&deg[da.y], 1);
      int r2 = atomicAdd(&deg[da.z], 1);
      int r3 = atomicAdd(&deg[da.w], 1);
      int r4 = atomicAdd(&deg[db.x], 1);
      int r5 = atomicAdd(&deg[db.y], 1);
      int r6 = atomicAdd(&deg[db.z], 1);
      int r7 = atomicAdd(&deg[db.w], 1);
      *(int4*)&rank[e0]     = make_int4(r0, r1, r2, r3);
      *(int4*)&rank[e0 + 4] = make_int4(r4, r5, r6, r7);
    }
    return;
  }

  const int gb = bid - DEG_BLOCKS;     // 0..781
  int mt, nt;
  if (gb < 768) {
    // groups of 16 bids cover 8 row-blocks x 2 channel tiles; twins differ by 8
    mt = ((gb >> 4) << 3) + (gb & 7);  // 0..383
    nt = (gb >> 3) & 1;
  } else {
    int l = gb - 768;                  // 0..13 -> row-blocks 384..390 x 2
    nt = (l >= 7) ? 1 : 0;
    mt = 384 + (nt ? l - 7 : l);
  }
  const int m0 = mt * 128;
  const int n0 = nt * 128;

  if (t < 128) {
    sAttnL[t] = attn_l[n0 + t];
    sAttnR[t] = attn_r[n0 + t];
  }
  // stage A: 128 rows x 32 float4 of feat -> bf16 (plain load: twin block L2-hits)
#pragma unroll
  for (int i = 0; i < 16; ++i) {
    int idx = t + i * 256;
    int row = idx >> 5;
    int c4 = idx & 31;
    int gn = m0 + row;
    float4 v = (gn < N_NODES_C)
                   ? *(const float4*)&feat[(size_t)gn * IN_FEATS_C + c4 * 4]
                   : make_float4(0.f, 0.f, 0.f, 0.f);
    ushort4 b;
    b.x = f2bf(v.x); b.y = f2bf(v.y); b.z = f2bf(v.z); b.w = f2bf(v.w);
    *(ushort4*)&sA[row * LDT + c4 * 4] = b;
  }
  __syncthreads();

  const int wid = t >> 6;
  const int lane = t & 63;
  const int quad = lane >> 4;
  const int l16 = lane & 15;
  const int wm = (wid & 1) * 64;
  const int wn = (wid >> 1) * 64;

  floatx4 acc[4][4];
#pragma unroll
  for (int i = 0; i < 4; ++i)
#pragma unroll
    for (int j = 0; j < 4; ++j) acc[i][j] = (floatx4){0.f, 0.f, 0.f, 0.f};

#pragma unroll
  for (int ks = 0; ks < 4; ++ks) {
    int k0 = ks * 32 + quad * 8;
    bf16x8 bfv[4];
#pragma unroll
    for (int n2 = 0; n2 < 4; ++n2)
      bfv[n2] = *(const bf16x8*)&Wbf[(size_t)(n0 + wn + n2 * 16 + l16) *
                                         IN_FEATS_C + k0];
    bf16x8 af[4];
#pragma unroll
    for (int m2 = 0; m2 < 4; ++m2)
      af[m2] = *(const bf16x8*)&sA[(wm + m2 * 16 + l16) * LDT + k0];
#pragma unroll
    for (int m2 = 0; m2 < 4; ++m2)
#pragma unroll
      for (int n2 = 0; n2 < 4; ++n2)
        acc[m2][n2] = __builtin_amdgcn_mfma_f32_16x16x32_bf16(
            af[m2], bfv[n2], acc[m2][n2], 0, 0, 0);
  }
  __syncthreads();

  // epilogue: D layout col=l16, row=quad*4+reg -> repack via LDS
#pragma unroll
  for (int m2 = 0; m2 < 4; ++m2)
#pragma unroll
    for (int n2 = 0; n2 < 4; ++n2)
#pragma unroll
      for (int r = 0; r < 4; ++r) {
        int row = wm + m2 * 16 + quad * 4 + r;
        int col = wn + n2 * 16 + l16;
        sA[row * LDT + col] = f2bf(acc[m2][n2][r]);
      }
  __syncthreads();

  // coalesced store of the bf16 tile
#pragma unroll
  for (int i = 0; i < 8; ++i) {
    int idx = t + i * 256;
    int row = idx >> 4;
    int ch = idx & 15;
    int gn = m0 + row;
    if (gn < N_NODES_C) {
      *(uint4*)&feat_hd_bf[(size_t)gn * HD_C + n0 + ch * 8] =
          *(const uint4*)&sA[row * LDT + ch * 8];
    }
  }

  // fused el/er: thread t -> row t>>1, head-pair t&1 (2 heads x 32 ch)
  {
    int row = t >> 1;
    int hh = t & 1;
    int gn = m0 + row;
    if (gn < N_NODES_C) {
      const unsigned short* pr = &sA[row * LDT + hh * 64];
      const float* al = &sAttnL[hh * 64];
      const float* ar = &sAttnR[hh * 64];
      float el0 = 0.f, el1 = 0.f, er0 = 0.f, er1 = 0.f;
#pragma unroll
      for (int d8 = 0; d8 < 4; ++d8) {
        bf16x8 v0 = *(const bf16x8*)&pr[d8 * 8];
        bf16x8 v1 = *(const bf16x8*)&pr[32 + d8 * 8];
#pragma unroll
        for (int j = 0; j < 8; ++j) {
          float f0 = bf2f((unsigned short)v0[j]);
          float f1 = bf2f((unsigned short)v1[j]);
          el0 = fmaf(f0, al[d8 * 8 + j], el0);
          er0 = fmaf(f0, ar[d8 * 8 + j], er0);
          el1 = fmaf(f1, al[32 + d8 * 8 + j], el1);
          er1 = fmaf(f1, ar[32 + d8 * 8 + j], er1);
        }
      }
      int gh = nt * 4 + hh * 2;
      el[gn * HEADS_C + gh + 0] = el0;
      el[gn * HEADS_C + gh + 1] = el1;
      er[gn * HEADS_C + gh + 0] = er0;
      er[gn * HEADS_C + gh + 1] = er1;
    }
  }
}

// ============ scan1: emits packed {row_start_incl, deg} int2 ============
__global__ __launch_bounds__(256) void scan1_kernel(
    const int* __restrict__ deg, int2* __restrict__ rsd,
    int* __restrict__ bsum) {
  __shared__ int s[256];
  int b = blockIdx.x, t = threadIdx.x;
  int i0 = b * 1024 + t * 4;
  int d0 = 0, d1 = 0, d2 = 0, d3 = 0;
  if (i0 + 4 <= N_NODES_C) {
    int4 d = *(const int4*)&deg[i0];
    d0 = d.x; d1 = d.y; d2 = d.z; d3 = d.w;
  } else {
    if (i0 + 0 < N_NODES_C) d0 = deg[i0 + 0];
    if (i0 + 1 < N_NODES_C) d1 = deg[i0 + 1];
    if (i0 + 2 < N_NODES_C) d2 = deg[i0 + 2];
    if (i0 + 3 < N_NODES_C) d3 = deg[i0 + 3];
  }
  int l1 = d0, l2 = l1 + d1, l3 = l2 + d2, l4 = l3 + d3;
  s[t] = l4;
  __syncthreads();
#pragma unroll
  for (int off = 1; off < 256; off <<= 1) {
    int add = (t >= off) ? s[t - off] : 0;
    __syncthreads();
    s[t] += add;
    __syncthreads();
  }
  int excl = s[t] - l4;
  if (i0 + 0 < N_NODES_C) rsd[i0 + 0] = make_int2(excl + l1, d0);
  if (i0 + 1 < N_NODES_C) rsd[i0 + 1] = make_int2(excl + l2, d1);
  if (i0 + 2 < N_NODES_C) rsd[i0 + 2] = make_int2(excl + l3, d2);
  if (i0 + 3 < N_NODES_C) rsd[i0 + 3] = make_int2(excl + l4, d3);
  if (t == 255) bsum[b] = s[255];
}

// ============ scatter: atomic-free, 4 edges/thread ============
// nt loads for the three pure streams (dst/rank/src, 9.6 MB never re-read)
// keep L2 for the rsd table and the scattered csr_src write-combining lines.
__global__ __launch_bounds__(256) void scatter_kernel(
    const int* __restrict__ src, const int* __restrict__ dst,
    const int2* __restrict__ rsd, const int* __restrict__ bsum,
    const int* __restrict__ rank, int* __restrict__ csr_src) {
  __shared__ int sboff[64];
  boff_scan(bsum, sboff);
  int base = (blockIdx.x * 256 + threadIdx.x) * 4;
  if (base >= N_EDGES_C) return;           // N_EDGES_C % 4 == 0 -> full int4
  intx4 d4 = __builtin_nontemporal_load((const intx4*)&dst[base]);
  intx4 r4 = __builtin_nontemporal_load((const intx4*)&rank[base]);
  intx4 s4 = __builtin_nontemporal_load((const intx4*)&src[base]);
  int2 v0 = rsd[d4[0]];
  int2 v1 = rsd[d4[1]];
  int2 v2 = rsd[d4[2]];
  int2 v3 = rsd[d4[3]];
  csr_src[v0.x - v0.y + sboff[d4[0] >> 10] + r4[0]] = s4[0];
  csr_src[v1.x - v1.y + sboff[d4[1] >> 10] + r4[1]] = s4[1];
  csr_src[v2.x - v2.y + sboff[d4[2] >> 10] + r4[2]] = s4[2];
  csr_src[v3.x - v3.y + sboff[d4[3] >> 10] + r4[3]] = s4[3];
}

// ============ aggregation over CSR: wave per dst node (round-2 structure) ============
// Floor established over SIX structural variants (69.4/87/73.4/69.5/68.2/201):
// ~68-70 us, ~211 MB fetch @ ~3.9 TB/s effective random-gather rate. The
// XCD-sharded variant (r9) proved residency is achievable (fetch 211->40 MB)
// but costs 3x in loop redundancy — do not touch.
__global__ __launch_bounds__(256) void agg_csr_kernel(
    const unsigned short* __restrict__ feat_hd_bf, const float* __restrict__ el,
    const float* __restrict__ er, const int2* __restrict__ rsd,
    const int* __restrict__ bsum, const int* __restrict__ csr_src,
    float* __restrict__ out) {
  __shared__ int sboff[64];
  boff_scan(bsum, sboff);
  int gid = blockIdx.x * 256 + threadIdx.x;
  int node = gid >> 6;
  int lane = threadIdx.x & 63;
  if (node >= N_NODES_C) return;
  int h = lane >> 3;
  int j8 = lane & 7;
  int hbase = lane & 56;               // h*8
  int c = lane * 4;
  float er_d = er[node * HEADS_C + h];
  int2 v = rsd[node];
  int dg = v.y;
  int rs = v.x - dg + sboff[node >> 10];
  float4 acc = make_float4(0.f, 0.f, 0.f, 0.f);
  float zsum = 0.f;

  int nb = (dg + 7) >> 3;              // number of 8-edge blocks (masked tail)
  if (nb > 0) {
    const int last = dg - 1;
    int myidx = csr_src[rs + min(j8, last)];
    for (int b = 0; b < nb; ++b) {
      int e0 = b * 8;
      ushort4 f[8];
#pragma unroll
      for (int j = 0; j < 8; ++j) {
        int sj = __shfl(myidx, j);
        f[j] = *(const ushort4*)&feat_hd_bf[(size_t)sj * HD_C + c];
      }
      float x = el[myidx * HEADS_C + h] + er_d;
      x = x > 0.f ? x : NEG_SLOPE_C * x;
      float wv = (e0 + j8 < dg) ? __expf(x) : 0.f;
      int nidx = csr_src[rs + min(e0 + 8 + j8, last)];
      float wj[8];
#pragma unroll
      for (int j = 0; j < 8; ++j) wj[j] = __shfl(wv, hbase + j);
      zsum += ((wj[0] + wj[1]) + (wj[2] + wj[3])) +
              ((wj[4] + wj[5]) + (wj[6] + wj[7]));
#pragma unroll
      for (int j = 0; j < 8; ++j) {
        acc.x = fmaf(wj[j], bf2f(f[j].x), acc.x);
        acc.y = fmaf(wj[j], bf2f(f[j].y), acc.y);
        acc.z = fmaf(wj[j], bf2f(f[j].z), acc.z);
        acc.w = fmaf(wj[j], bf2f(f[j].w), acc.w);
      }
      myidx = nidx;
    }
  }

  float inv = (dg > 0) ? 1.f / zsum : 0.f;
  acc.x *= inv; acc.y *= inv; acc.z *= inv; acc.w *= inv;
  *(float4*)&out[(size_t)node * HD_C + c] = acc;
}

extern "C" void kernel_launch(void* const* d_in, const int* in_sizes, int n_in,
                              void* d_out, int out_size, void* d_ws, size_t ws_size,
                              hipStream_t stream) {
  const float* feat   = (const float*)d_in[0];
  const float* W      = (const float*)d_in[1];
  const float* attn_l = (const float*)d_in[2];
  const float* attn_r = (const float*)d_in[3];
  const int* src      = (const int*)d_in[4];
  const int* dst      = (const int*)d_in[5];
  float* out = (float*)d_out;

  char* ws = (char*)d_ws;
  unsigned short* feat_hd_bf = (unsigned short*)ws;  ws += (size_t)N_NODES_C * HD_C * 2;     // 25.6 MB
  float* el      = (float*)ws;                       ws += (size_t)N_NODES_C * HEADS_C * 4;  // 1.6 MB
  float* er      = (float*)ws;                       ws += (size_t)N_NODES_C * HEADS_C * 4;  // 1.6 MB
  int* deg       = (int*)ws;                         ws += (size_t)N_NODES_C * 4;
  int2* rsd      = (int2*)ws;                        ws += (size_t)N_NODES_C * 8;            // packed {row_start, deg}
  int* bsum      = (int*)ws;                         ws += 64 * 4;
  int* csr_src   = (int*)ws;                         ws += (size_t)N_EDGES_C * 4;            // 3.2 MB
  int* rank      = (int*)ws;                         ws += (size_t)N_EDGES_C * 4;            // 3.2 MB
  unsigned short* Wbf = (unsigned short*)ws;         ws += (size_t)HD_C * IN_FEATS_C * 2;    // 64 KB

  prep_kernel<<<81, 256, 0, stream>>>(W, Wbf, deg);

  front_kernel<<<K1_GRID, 256, 0, stream>>>(feat, Wbf, attn_l, attn_r, dst,
                                            feat_hd_bf, el, er, deg, rank);

  scan1_kernel<<<SCAN_NBLK, 256, 0, stream>>>(deg, rsd, bsum);

  scatter_kernel<<<(N_EDGES_C / 4 + 255) / 256, 256, 0, stream>>>(
      src, dst, rsd, bsum, rank, csr_src);

  agg_csr_kernel<<<(N_NODES_C + 3) / 4, 256, 0, stream>>>(
      feat_hd_bf, el, er, rsd, bsum, csr_src, out);
}

// Round 11
// 223.599 us; speedup vs baseline: 1.5623x; 1.0195x over previous
//
#include <hip/hip_runtime.h>

#define N_NODES_C 50000
#define N_EDGES_C 800000
#define IN_FEATS_C 128
#define HEADS_C 8
#define HD_C 256            // HEADS * OUT_FEATS
#define NEG_SLOPE_C 0.2f
#define SCAN_NBLK 49        // ceil(50000/1024)
#define LDT 136             // LDS row stride in shorts (272 B = 17*16, 16B-aligned)

#define GEMM_BLOCKS 782     // ceil(50000/128) * 2 channel tiles
#define DEG_BLOCKS 242
#define K1_GRID (GEMM_BLOCKS + DEG_BLOCKS)   // 1024

typedef __attribute__((ext_vector_type(8))) short bf16x8;
typedef __attribute__((ext_vector_type(4))) float floatx4;

__device__ inline unsigned short f2bf(float f) {
  unsigned int u = __float_as_uint(f);
  unsigned int r = (u + 0x7FFFu + ((u >> 16) & 1u)) >> 16;   // RNE
  return (unsigned short)r;
}
__device__ inline float bf2f(unsigned short s) {
  unsigned int u = ((unsigned int)s) << 16;
  return __uint_as_float(u);
}

// 49-entry exclusive scan of bsum into sboff[64] (first wave only, then barrier)
__device__ inline void boff_scan(const int* __restrict__ bsum, int* sboff) {
  int t = threadIdx.x;
  if (t < 64) {
    int own = (t < SCAN_NBLK) ? bsum[t] : 0;
    int v = own;
#pragma unroll
    for (int off = 1; off < 64; off <<= 1) {
      int u = __shfl_up(v, off);
      if (t >= off) v += u;
    }
    sboff[t] = v - own;   // exclusive
  }
  __syncthreads();
}

// ============ prep: fused {W fp32->bf16 conversion, deg zeroing} ============
// blocks 0..31: convert W (32768 floats). blocks 32..80: zero deg (50000 ints).
__global__ __launch_bounds__(256) void prep_kernel(
    const float* __restrict__ W, unsigned short* __restrict__ Wbf,
    int* __restrict__ deg) {
  int b = blockIdx.x, t = threadIdx.x;
  if (b < 32) {
    int i = (b * 256 + t) * 4;
    float4 v = *(const float4*)&W[i];
    ushort4 o;
    o.x = f2bf(v.x); o.y = f2bf(v.y); o.z = f2bf(v.z); o.w = f2bf(v.w);
    *(ushort4*)&Wbf[i] = o;
  } else {
    int i = ((b - 32) * 256 + t) * 4;
    if (i < N_NODES_C) {
      if (i + 4 <= N_NODES_C)
        *(int4*)&deg[i] = make_int4(0, 0, 0, 0);
      else
        for (int k = i; k < N_NODES_C; ++k) deg[k] = 0;
    }
  }
}

// ============ K1: deg+rank histogram (0..241) || MFMA gemm + fused el/er ============
// GEMM block mapping pairs the two channel tiles of a row-block 8 bids apart:
// same XCD under round-robin dispatch and co-resident -> the twin's feat
// staging L2-hits instead of re-fetching 64 KB from HBM.
__global__ __launch_bounds__(256) void front_kernel(
    const float* __restrict__ feat, const unsigned short* __restrict__ Wbf,
    const float* __restrict__ attn_l, const float* __restrict__ attn_r,
    const int* __restrict__ dst,
    unsigned short* __restrict__ feat_hd_bf,
    float* __restrict__ el, float* __restrict__ er,
    int* __restrict__ deg, int* __restrict__ rank) {
  __shared__ __align__(16) unsigned short sA[128 * LDT];   // 34816 B; reused as sOut
  __shared__ float sAttnL[128];
  __shared__ float sAttnR[128];
  const int bid = blockIdx.x;
  const int t = threadIdx.x;

  if (bid < DEG_BLOCKS) {
    // ---- degree histogram + rank capture, 8 atomics in flight ----
    for (int e0 = (bid * 256 + t) * 8; e0 < N_EDGES_C; e0 += DEG_BLOCKS * 2048) {
      int4 da = *(const int4*)&dst[e0];
      int4 db = *(const int4*)&dst[e0 + 4];
      int r0 = atomicAdd(&deg[da.x], 1);
      int r1 = atomicAdd(&deg[da.y], 1);
      int r2 = atomicAdd(&deg[da.z], 1);
      int r3 = atomicAdd(&deg[da.w], 1);
      int r4 = atomicAdd(&deg[db.x], 1);
      int r5 = atomicAdd(&deg[db.y], 1);
      int r6 = atomicAdd(&deg[db.z], 1);
      int r7 = atomicAdd(&deg[db.w], 1);
      *(int4*)&rank[e0]     = make_int4(r0, r1, r2, r3);
      *(int4*)&rank[e0 + 4] = make_int4(r4, r5, r6, r7);
    }
    return;
  }

  const int gb = bid - DEG_BLOCKS;     // 0..781
  int mt, nt;
  if (gb < 768) {
    // groups of 16 bids cover 8 row-blocks x 2 channel tiles; twins differ by 8
    mt = ((gb >> 4) << 3) + (gb & 7);  // 0..383
    nt = (gb >> 3) & 1;
  } else {
    int l = gb - 768;                  // 0..13 -> row-blocks 384..390 x 2
    nt = (l >= 7) ? 1 : 0;
    mt = 384 + (nt ? l - 7 : l);
  }
  const int m0 = mt * 128;
  const int n0 = nt * 128;

  if (t < 128) {
    sAttnL[t] = attn_l[n0 + t];
    sAttnR[t] = attn_r[n0 + t];
  }
  // stage A: 128 rows x 32 float4 of feat -> bf16 (plain load: twin block L2-hits)
#pragma unroll
  for (int i = 0; i < 16; ++i) {
    int idx = t + i * 256;
    int row = idx >> 5;
    int c4 = idx & 31;
    int gn = m0 + row;
    float4 v = (gn < N_NODES_C)
                   ? *(const float4*)&feat[(size_t)gn * IN_FEATS_C + c4 * 4]
                   : make_float4(0.f, 0.f, 0.f, 0.f);
    ushort4 b;
    b.x = f2bf(v.x); b.y = f2bf(v.y); b.z = f2bf(v.z); b.w = f2bf(v.w);
    *(ushort4*)&sA[row * LDT + c4 * 4] = b;
  }
  __syncthreads();

  const int wid = t >> 6;
  const int lane = t & 63;
  const int quad = lane >> 4;
  const int l16 = lane & 15;
  const int wm = (wid & 1) * 64;
  const int wn = (wid >> 1) * 64;

  floatx4 acc[4][4];
#pragma unroll
  for (int i = 0; i < 4; ++i)
#pragma unroll
    for (int j = 0; j < 4; ++j) acc[i][j] = (floatx4){0.f, 0.f, 0.f, 0.f};

#pragma unroll
  for (int ks = 0; ks < 4; ++ks) {
    int k0 = ks * 32 + quad * 8;
    bf16x8 bfv[4];
#pragma unroll
    for (int n2 = 0; n2 < 4; ++n2)
      bfv[n2] = *(const bf16x8*)&Wbf[(size_t)(n0 + wn + n2 * 16 + l16) *
                                         IN_FEATS_C + k0];
    bf16x8 af[4];
#pragma unroll
    for (int m2 = 0; m2 < 4; ++m2)
      af[m2] = *(const bf16x8*)&sA[(wm + m2 * 16 + l16) * LDT + k0];
#pragma unroll
    for (int m2 = 0; m2 < 4; ++m2)
#pragma unroll
      for (int n2 = 0; n2 < 4; ++n2)
        acc[m2][n2] = __builtin_amdgcn_mfma_f32_16x16x32_bf16(
            af[m2], bfv[n2], acc[m2][n2], 0, 0, 0);
  }
  __syncthreads();

  // epilogue: D layout col=l16, row=quad*4+reg -> repack via LDS
#pragma unroll
  for (int m2 = 0; m2 < 4; ++m2)
#pragma unroll
    for (int n2 = 0; n2 < 4; ++n2)
#pragma unroll
      for (int r = 0; r < 4; ++r) {
        int row = wm + m2 * 16 + quad * 4 + r;
        int col = wn + n2 * 16 + l16;
        sA[row * LDT + col] = f2bf(acc[m2][n2][r]);
      }
  __syncthreads();

  // coalesced store of the bf16 tile
#pragma unroll
  for (int i = 0; i < 8; ++i) {
    int idx = t + i * 256;
    int row = idx >> 4;
    int ch = idx & 15;
    int gn = m0 + row;
    if (gn < N_NODES_C) {
      *(uint4*)&feat_hd_bf[(size_t)gn * HD_C + n0 + ch * 8] =
          *(const uint4*)&sA[row * LDT + ch * 8];
    }
  }

  // fused el/er: thread t -> row t>>1, head-pair t&1 (2 heads x 32 ch)
  // vectorized b128 LDS reads (8x bf16x8) instead of 128 scalar ds_read_u16
  {
    int row = t >> 1;
    int hh = t & 1;
    int gn = m0 + row;
    if (gn < N_NODES_C) {
      const unsigned short* pr = &sA[row * LDT + hh * 64];
      const float* al = &sAttnL[hh * 64];
      const float* ar = &sAttnR[hh * 64];
      float el0 = 0.f, el1 = 0.f, er0 = 0.f, er1 = 0.f;
#pragma unroll
      for (int d8 = 0; d8 < 4; ++d8) {
        bf16x8 v0 = *(const bf16x8*)&pr[d8 * 8];        // head gh:   ch d8*8..+8
        bf16x8 v1 = *(const bf16x8*)&pr[32 + d8 * 8];   // head gh+1
#pragma unroll
        for (int j = 0; j < 8; ++j) {
          float f0 = bf2f((unsigned short)v0[j]);
          float f1 = bf2f((unsigned short)v1[j]);
          el0 = fmaf(f0, al[d8 * 8 + j], el0);
          er0 = fmaf(f0, ar[d8 * 8 + j], er0);
          el1 = fmaf(f1, al[32 + d8 * 8 + j], el1);
          er1 = fmaf(f1, ar[32 + d8 * 8 + j], er1);
        }
      }
      int gh = nt * 4 + hh * 2;
      el[gn * HEADS_C + gh + 0] = el0;
      el[gn * HEADS_C + gh + 1] = el1;
      er[gn * HEADS_C + gh + 0] = er0;
      er[gn * HEADS_C + gh + 1] = er1;
    }
  }
}

// ============ scan1: emits packed {row_start_incl, deg} int2 ============
__global__ __launch_bounds__(256) void scan1_kernel(
    const int* __restrict__ deg, int2* __restrict__ rsd,
    int* __restrict__ bsum) {
  __shared__ int s[256];
  int b = blockIdx.x, t = threadIdx.x;
  int i0 = b * 1024 + t * 4;
  int d0 = 0, d1 = 0, d2 = 0, d3 = 0;
  if (i0 + 4 <= N_NODES_C) {
    int4 d = *(const int4*)&deg[i0];
    d0 = d.x; d1 = d.y; d2 = d.z; d3 = d.w;
  } else {
    if (i0 + 0 < N_NODES_C) d0 = deg[i0 + 0];
    if (i0 + 1 < N_NODES_C) d1 = deg[i0 + 1];
    if (i0 + 2 < N_NODES_C) d2 = deg[i0 + 2];
    if (i0 + 3 < N_NODES_C) d3 = deg[i0 + 3];
  }
  int l1 = d0, l2 = l1 + d1, l3 = l2 + d2, l4 = l3 + d3;
  s[t] = l4;
  __syncthreads();
#pragma unroll
  for (int off = 1; off < 256; off <<= 1) {
    int add = (t >= off) ? s[t - off] : 0;
    __syncthreads();
    s[t] += add;
    __syncthreads();
  }
  int excl = s[t] - l4;
  if (i0 + 0 < N_NODES_C) rsd[i0 + 0] = make_int2(excl + l1, d0);
  if (i0 + 1 < N_NODES_C) rsd[i0 + 1] = make_int2(excl + l2, d1);
  if (i0 + 2 < N_NODES_C) rsd[i0 + 2] = make_int2(excl + l3, d2);
  if (i0 + 3 < N_NODES_C) rsd[i0 + 3] = make_int2(excl + l4, d3);
  if (t == 255) bsum[b] = s[255];
}

// ============ scatter: atomic-free, 4 edges/thread (plain loads — nt hurt, r10) ============
__global__ __launch_bounds__(256) void scatter_kernel(
    const int* __restrict__ src, const int* __restrict__ dst,
    const int2* __restrict__ rsd, const int* __restrict__ bsum,
    const int* __restrict__ rank, int* __restrict__ csr_src) {
  __shared__ int sboff[64];
  boff_scan(bsum, sboff);
  int base = (blockIdx.x * 256 + threadIdx.x) * 4;
  if (base >= N_EDGES_C) return;           // N_EDGES_C % 4 == 0 -> full int4
  int4 d4 = *(const int4*)&dst[base];
  int4 r4 = *(const int4*)&rank[base];
  int4 s4 = *(const int4*)&src[base];
  int2 v0 = rsd[d4.x];
  int2 v1 = rsd[d4.y];
  int2 v2 = rsd[d4.z];
  int2 v3 = rsd[d4.w];
  csr_src[v0.x - v0.y + sboff[d4.x >> 10] + r4.x] = s4.x;
  csr_src[v1.x - v1.y + sboff[d4.y >> 10] + r4.y] = s4.y;
  csr_src[v2.x - v2.y + sboff[d4.z >> 10] + r4.z] = s4.z;
  csr_src[v3.x - v3.y + sboff[d4.w >> 10] + r4.w] = s4.w;
}

// ============ aggregation over CSR: wave per dst node (round-2 structure) ============
// Floor established over six structural variants (69.4/87/73.4/69.5/68.2/201):
// ~68-70 us, ~211 MB fetch @ ~3.9 TB/s effective random-gather rate.
__global__ __launch_bounds__(256) void agg_csr_kernel(
    const unsigned short* __restrict__ feat_hd_bf, const float* __restrict__ el,
    const float* __restrict__ er, const int2* __restrict__ rsd,
    const int* __restrict__ bsum, const int* __restrict__ csr_src,
    float* __restrict__ out) {
  __shared__ int sboff[64];
  boff_scan(bsum, sboff);
  int gid = blockIdx.x * 256 + threadIdx.x;
  int node = gid >> 6;
  int lane = threadIdx.x & 63;
  if (node >= N_NODES_C) return;
  int h = lane >> 3;
  int j8 = lane & 7;
  int hbase = lane & 56;               // h*8
  int c = lane * 4;
  float er_d = er[node * HEADS_C + h];
  int2 v = rsd[node];
  int dg = v.y;
  int rs = v.x - dg + sboff[node >> 10];
  float4 acc = make_float4(0.f, 0.f, 0.f, 0.f);
  float zsum = 0.f;

  int nb = (dg + 7) >> 3;              // number of 8-edge blocks (masked tail)
  if (nb > 0) {
    const int last = dg - 1;
    int myidx = csr_src[rs + min(j8, last)];
    for (int b = 0; b < nb; ++b) {
      int e0 = b * 8;
      ushort4 f[8];
#pragma unroll
      for (int j = 0; j < 8; ++j) {
        int sj = __shfl(myidx, j);
        f[j] = *(const ushort4*)&feat_hd_bf[(size_t)sj * HD_C + c];
      }
      float x = el[myidx * HEADS_C + h] + er_d;
      x = x > 0.f ? x : NEG_SLOPE_C * x;
      float wv = (e0 + j8 < dg) ? __expf(x) : 0.f;
      int nidx = csr_src[rs + min(e0 + 8 + j8, last)];
      float wj[8];
#pragma unroll
      for (int j = 0; j < 8; ++j) wj[j] = __shfl(wv, hbase + j);
      zsum += ((wj[0] + wj[1]) + (wj[2] + wj[3])) +
              ((wj[4] + wj[5]) + (wj[6] + wj[7]));
#pragma unroll
      for (int j = 0; j < 8; ++j) {
        acc.x = fmaf(wj[j], bf2f(f[j].x), acc.x);
        acc.y = fmaf(wj[j], bf2f(f[j].y), acc.y);
        acc.z = fmaf(wj[j], bf2f(f[j].z), acc.z);
        acc.w = fmaf(wj[j], bf2f(f[j].w), acc.w);
      }
      myidx = nidx;
    }
  }

  float inv = (dg > 0) ? 1.f / zsum : 0.f;
  acc.x *= inv; acc.y *= inv; acc.z *= inv; acc.w *= inv;
  *(float4*)&out[(size_t)node * HD_C + c] = acc;
}

extern "C" void kernel_launch(void* const* d_in, const int* in_sizes, int n_in,
                              void* d_out, int out_size, void* d_ws, size_t ws_size,
                              hipStream_t stream) {
  const float* feat   = (const float*)d_in[0];
  const float* W      = (const float*)d_in[1];
  const float* attn_l = (const float*)d_in[2];
  const float* attn_r = (const float*)d_in[3];
  const int* src      = (const int*)d_in[4];
  const int* dst      = (const int*)d_in[5];
  float* out = (float*)d_out;

  char* ws = (char*)d_ws;
  unsigned short* feat_hd_bf = (unsigned short*)ws;  ws += (size_t)N_NODES_C * HD_C * 2;     // 25.6 MB
  float* el      = (float*)ws;                       ws += (size_t)N_NODES_C * HEADS_C * 4;  // 1.6 MB
  float* er      = (float*)ws;                       ws += (size_t)N_NODES_C * HEADS_C * 4;  // 1.6 MB
  int* deg       = (int*)ws;                         ws += (size_t)N_NODES_C * 4;
  int2* rsd      = (int2*)ws;                        ws += (size_t)N_NODES_C * 8;            // packed {row_start, deg}
  int* bsum      = (int*)ws;                         ws += 64 * 4;
  int* csr_src   = (int*)ws;                         ws += (size_t)N_EDGES_C * 4;            // 3.2 MB
  int* rank      = (int*)ws;                         ws += (size_t)N_EDGES_C * 4;            // 3.2 MB
  unsigned short* Wbf = (unsigned short*)ws;         ws += (size_t)HD_C * IN_FEATS_C * 2;    // 64 KB

  prep_kernel<<<81, 256, 0, stream>>>(W, Wbf, deg);

  front_kernel<<<K1_GRID, 256, 0, stream>>>(feat, Wbf, attn_l, attn_r, dst,
                                            feat_hd_bf, el, er, deg, rank);

  scan1_kernel<<<SCAN_NBLK, 256, 0, stream>>>(deg, rsd, bsum);

  scatter_kernel<<<(N_EDGES_C / 4 + 255) / 256, 256, 0, stream>>>(
      src, dst, rsd, bsum, rank, csr_src);

  agg_csr_kernel<<<(N_NODES_C + 3) / 4, 256, 0, stream>>>(
      feat_hd_bf, el, er, rsd, bsum, csr_src, out);
}